// Round 5
// baseline (37160.974 us; speedup 1.0000x reference)
//
#include <hip/hip_runtime.h>

constexpr int TT  = 2048;  // timesteps
constexpr int NB  = 128;   // batch
constexpr int NI  = 64;    // input size
constexpr int NH  = 256;   // hidden
constexpr int NWG = 256;   // 128 layer-0 + 128 layer-1
constexpr int NTHR = 512;
constexpr int R0  = 4;     // h0 ring slots
constexpr int R1  = 8;     // h1 ring slots
constexpr int HLAG = 4;    // head lag (reads h1(s-4) at layer-0 step s)

// Monotonic aggregate counters, one cacheline per (layer, b-half).
// Zero at load; reset at kernel end -> graph-replay safe.
__device__ unsigned g_cnt0[2 * 32];   // [bh*32]: layer-0 h0 publishes
__device__ unsigned g_cnt1[2 * 32];   // [bh*32]: layer-1 h1 publishes
__device__ unsigned g_cnt = 0, g_gen = 0;

__device__ __forceinline__ float sigm(float v) { return 1.0f / (1.0f + __expf(-v)); }

// LLC-coherent (agent-scope relaxed) accessors for cross-WG h data.
__device__ __forceinline__ float ldh1(const float* p) {
    return __hip_atomic_load(p, __ATOMIC_RELAXED, __HIP_MEMORY_SCOPE_AGENT);
}
__device__ __forceinline__ void sth(float* p, float v) {
    __hip_atomic_store(p, v, __ATOMIC_RELAXED, __HIP_MEMORY_SCOPE_AGENT);
}
// Fire-and-forget producer bump (no return value -> no wave stall).
__device__ __forceinline__ void bump(unsigned* p) {
    (void)__hip_atomic_fetch_add(p, 1u, __ATOMIC_RELAXED, __HIP_MEMORY_SCOPE_AGENT);
}
// Single-line monotonic poll (whole wave, uniform address -> 1 transaction).
__device__ __forceinline__ void waitge(unsigned* p, unsigned tgt) {
    for (;;) {
        unsigned v = __hip_atomic_load(p, __ATOMIC_RELAXED, __HIP_MEMORY_SCOPE_AGENT);
        if ((int)(v - tgt) >= 0) break;
        __builtin_amdgcn_s_sleep(1);
    }
}

// Counter barrier, used ONLY at kernel end for the reset protocol.
__device__ __forceinline__ void gridbar(unsigned k, bool last) {
    __syncthreads();
    if (threadIdx.x == 0) {
        __threadfence();
        unsigned a = __hip_atomic_fetch_add(&g_cnt, 1u, __ATOMIC_ACQ_REL,
                                            __HIP_MEMORY_SCOPE_AGENT);
        if (a == k * NWG - 1u) {
            if (last) {
                __hip_atomic_store(&g_cnt, 0u, __ATOMIC_RELAXED, __HIP_MEMORY_SCOPE_AGENT);
                __hip_atomic_store(&g_gen, 0u, __ATOMIC_RELEASE, __HIP_MEMORY_SCOPE_AGENT);
            } else {
                __hip_atomic_store(&g_gen, k, __ATOMIC_RELEASE, __HIP_MEMORY_SCOPE_AGENT);
            }
        } else if (!last) {
            while (__hip_atomic_load(&g_gen, __ATOMIC_RELAXED,
                                     __HIP_MEMORY_SCOPE_AGENT) < k)
                __builtin_amdgcn_s_sleep(1);
        }
        __threadfence();
    }
    __syncthreads();
}

// Partial dot over h stored [k][b]: 8 rows (2 j x 4 gates, j = jA, jA+1),
// k in [kbase, kbase+klen), one b column per lane. Weight addresses are
// wave-uniform -> scalar (SGPR) loads; h via LLC-coherent dword loads.
// acc[r], r = jloc*4 + gate.
__device__ __forceinline__ void partH(const float* __restrict__ W, int jA,
                                      int kbase, int klen,
                                      const float* __restrict__ hsrc, int bg,
                                      float* acc) {
    const float* w0 = W + (size_t)(0 * NH + jA) * NH;
    const float* w1 = W + (size_t)(1 * NH + jA) * NH;
    const float* w2 = W + (size_t)(2 * NH + jA) * NH;
    const float* w3 = W + (size_t)(3 * NH + jA) * NH;
    const float* hp = hsrc + bg;
    #pragma unroll 4
    for (int kk = kbase; kk < kbase + klen; kk += 4) {
        float4 a0 = *(const float4*)(w0 + kk);
        float4 a1 = *(const float4*)(w1 + kk);
        float4 a2 = *(const float4*)(w2 + kk);
        float4 a3 = *(const float4*)(w3 + kk);
        float4 b0 = *(const float4*)(w0 + NH + kk);
        float4 b1 = *(const float4*)(w1 + NH + kk);
        float4 b2 = *(const float4*)(w2 + NH + kk);
        float4 b3 = *(const float4*)(w3 + NH + kk);
        float h0 = ldh1(hp + (size_t)(kk + 0) * NB);
        float h1 = ldh1(hp + (size_t)(kk + 1) * NB);
        float h2 = ldh1(hp + (size_t)(kk + 2) * NB);
        float h3 = ldh1(hp + (size_t)(kk + 3) * NB);
        acc[0] += a0.x*h0 + a0.y*h1 + a0.z*h2 + a0.w*h3;
        acc[1] += a1.x*h0 + a1.y*h1 + a1.z*h2 + a1.w*h3;
        acc[2] += a2.x*h0 + a2.y*h1 + a2.z*h2 + a2.w*h3;
        acc[3] += a3.x*h0 + a3.y*h1 + a3.z*h2 + a3.w*h3;
        acc[4] += b0.x*h0 + b0.y*h1 + b0.z*h2 + b0.w*h3;
        acc[5] += b1.x*h0 + b1.y*h1 + b1.z*h2 + b1.w*h3;
        acc[6] += b2.x*h0 + b2.y*h1 + b2.z*h2 + b2.w*h3;
        acc[7] += b3.x*h0 + b3.y*h1 + b3.z*h2 + b3.w*h3;
    }
}

// Partial dot over x stored [b][k] (k contiguous), K = NI. Normal cached loads.
__device__ __forceinline__ void partX(const float* __restrict__ W, int jA,
                                      int kbase, int klen,
                                      const float* __restrict__ xp, int bg,
                                      float* acc) {
    const float* w0 = W + (size_t)(0 * NH + jA) * NI;
    const float* w1 = W + (size_t)(1 * NH + jA) * NI;
    const float* w2 = W + (size_t)(2 * NH + jA) * NI;
    const float* w3 = W + (size_t)(3 * NH + jA) * NI;
    const float* xr = xp + (size_t)bg * NI;
    #pragma unroll
    for (int kk = kbase; kk < kbase + klen; kk += 4) {
        float4 a0 = *(const float4*)(w0 + kk);
        float4 a1 = *(const float4*)(w1 + kk);
        float4 a2 = *(const float4*)(w2 + kk);
        float4 a3 = *(const float4*)(w3 + kk);
        float4 b0 = *(const float4*)(w0 + NI + kk);
        float4 b1 = *(const float4*)(w1 + NI + kk);
        float4 b2 = *(const float4*)(w2 + NI + kk);
        float4 b3 = *(const float4*)(w3 + NI + kk);
        float4 xv = *(const float4*)(xr + kk);
        acc[0] += a0.x*xv.x + a0.y*xv.y + a0.z*xv.z + a0.w*xv.w;
        acc[1] += a1.x*xv.x + a1.y*xv.y + a1.z*xv.z + a1.w*xv.w;
        acc[2] += a2.x*xv.x + a2.y*xv.y + a2.z*xv.z + a2.w*xv.w;
        acc[3] += a3.x*xv.x + a3.y*xv.y + a3.z*xv.z + a3.w*xv.w;
        acc[4] += b0.x*xv.x + b0.y*xv.y + b0.z*xv.z + b0.w*xv.w;
        acc[5] += b1.x*xv.x + b1.y*xv.y + b1.z*xv.z + b1.w*xv.w;
        acc[6] += b2.x*xv.x + b2.y*xv.y + b2.z*xv.z + b2.w*xv.w;
        acc[7] += b3.x*xv.x + b3.y*xv.y + b3.z*xv.z + b3.w*xv.w;
    }
}

// Grid: 256 WGs x 512 thr (1 WG/CU). gid<128: layer 0 (+head), else layer 1.
// WG (js, bh) owns j rows [4js, 4js+4) x batch half [64bh, 64bh+64).
// Waves: w&1 = j-pair half, (w>>1)&1 = k-quarter, w>>2 = matrix part.
// Combine threads (tid<256) own (jl, b) and keep c in a register throughout.
__global__ void __launch_bounds__(NTHR, 1) lstm2(
    const float* __restrict__ x,
    const float* __restrict__ h0in, const float* __restrict__ c0in,
    const float* __restrict__ Wih0, const float* __restrict__ Whh0,
    const float* __restrict__ bih0, const float* __restrict__ bhh0,
    const float* __restrict__ Wih1, const float* __restrict__ Whh1,
    const float* __restrict__ bih1, const float* __restrict__ bhh1,
    const float* __restrict__ Wlin, const float* __restrict__ blin,
    float* __restrict__ out,
    float* __restrict__ h0T, float* __restrict__ h1T)
{
    __shared__ __align__(16) float zp[8][64][8];   // [wave][b][row] partials, 16 KB
    __shared__ float red[4];

    const int tid  = threadIdx.x;
    const int gid  = blockIdx.x;
    const bool is1 = gid >= 128;
    const int idx  = is1 ? gid - 128 : gid;
    const int js   = idx >> 1;
    const int bh   = idx & 1;
    const int j0   = js * 4;
    const int lane = tid & 63;
    const int wv   = __builtin_amdgcn_readfirstlane(tid >> 6);
    const int jh   = wv & 1;
    const int kq   = (wv >> 1) & 1;
    const int hi   = wv >> 2;            // 0: first matrix part, 1: second
    const int bg   = bh * 64 + lane;     // partial lanes' global b
    const int jA   = j0 + 2 * jh;

    unsigned* ownc   = is1 ? &g_cnt1[bh * 32] : &g_cnt0[bh * 32];
    unsigned* crossc = is1 ? &g_cnt0[bh * 32] : &g_cnt1[bh * 32];

    // combine-role mapping
    const int cb  = tid & 63;
    const int cjl = tid >> 6;            // valid for tid<256: 0..3
    const int cj  = j0 + (cjl & 3);
    const int cbg = bh * 64 + cb;

    float c = 0.f;
    float4 bsv = make_float4(0.f, 0.f, 0.f, 0.f);
    if (tid < 256) {
        const float* bi = is1 ? bih1 : bih0;
        const float* bb = is1 ? bhh1 : bhh0;
        bsv.x = bi[0 * NH + cj] + bb[0 * NH + cj];
        bsv.y = bi[1 * NH + cj] + bb[1 * NH + cj];
        bsv.z = bi[2 * NH + cj] + bb[2 * NH + cj];
        bsv.w = bi[3 * NH + cj] + bb[3 * NH + cj];
        c = c0in[(is1 ? 1 : 0) * NB * NH + cbg * NH + cj];
        float* hT = is1 ? h1T : h0T;
        const int islot = is1 ? (R1 - 1) : (R0 - 1);
        sth(&hT[(size_t)islot * NH * NB + (size_t)cj * NB + cbg],
            h0in[(is1 ? 1 : 0) * NB * NH + cbg * NH + cj]);
    }
    const float blv = blin[0];
    asm volatile("s_waitcnt vmcnt(0)" ::: "memory");
    __syncthreads();
    if (tid == 0) bump(ownc);   // init publish: counter hits 64 per (layer,bh)

    if (!is1) {
        // ================= layer 0 (+ head, lag HLAG) =================
        const int bhead = bh * 64 + js;
        for (int s = 0; s < TT + HLAG; ++s) {
            if (hi == 0) {                      // waves 0-3: need h0(s-1)
                if (s < TT) waitge(ownc, 64u * (unsigned)(s + 1));
            } else {                            // waves 4-7: ring throttle + head gate
                if (s >= 3) waitge(crossc, 64u * (unsigned)(s - 2));
            }
            if (s < TT) {
                float acc[8] = {0,0,0,0,0,0,0,0};
                if (hi == 0)
                    partH(Whh0, jA, kq * 128, 128,
                          h0T + (size_t)((s + R0 - 1) & (R0 - 1)) * NH * NB, bg, acc);
                else
                    partX(Wih0, jA, kq * 32, 32, x + (size_t)s * NB * NI, bg, acc);
                *(float4*)&zp[wv][lane][0] = make_float4(acc[0], acc[1], acc[2], acc[3]);
                *(float4*)&zp[wv][lane][4] = make_float4(acc[4], acc[5], acc[6], acc[7]);
            }
            __syncthreads();
            if (s < TT && tid < 256) {
                float4 z = bsv;
                const int jhc = cjl >> 1, jlc = cjl & 1;
                #pragma unroll
                for (int q = 0; q < 4; ++q) {
                    float4 v = *(const float4*)&zp[(q << 1) | jhc][cb][jlc << 2];
                    z.x += v.x; z.y += v.y; z.z += v.z; z.w += v.w;
                }
                float ig = sigm(z.x), fg = sigm(z.y);
                float gg = tanhf(z.z), og = sigm(z.w);
                c = fg * c + ig * gg;
                float hn = og * tanhf(c);
                sth(&h0T[(size_t)(s & (R0 - 1)) * NH * NB + (size_t)cj * NB + cbg], hn);
            }
            if (s >= HLAG && tid >= 256) {      // head partial, waves 4-7
                const int u = s - HLAG;
                const int k = tid - 256;
                float hp = Wlin[k] *
                    ldh1(h1T + (size_t)(u & (R1 - 1)) * NH * NB + (size_t)k * NB + bhead);
                #pragma unroll
                for (int off = 32; off; off >>= 1) hp += __shfl_down(hp, off);
                if (lane == 0) red[wv - 4] = hp;
            }
            asm volatile("s_waitcnt vmcnt(0)" ::: "memory");
            __syncthreads();
            if (s < TT && tid == 0) bump(ownc);
            if (s >= HLAG && tid == 256)
                out[(size_t)(s - HLAG) * NB + bhead] =
                    red[0] + red[1] + red[2] + red[3] + blv;
        }
    } else {
        // ================= layer 1 =================
        for (int t = 0; t < TT; ++t) {
            if (hi == 0) waitge(crossc, 64u * (unsigned)(t + 2));  // h0(t)
            else         waitge(ownc,   64u * (unsigned)(t + 1));  // h1(t-1)

            float acc[8] = {0,0,0,0,0,0,0,0};
            if (hi == 0)
                partH(Wih1, jA, kq * 128, 128,
                      h0T + (size_t)(t & (R0 - 1)) * NH * NB, bg, acc);
            else
                partH(Whh1, jA, kq * 128, 128,
                      h1T + (size_t)((t + R1 - 1) & (R1 - 1)) * NH * NB, bg, acc);
            *(float4*)&zp[wv][lane][0] = make_float4(acc[0], acc[1], acc[2], acc[3]);
            *(float4*)&zp[wv][lane][4] = make_float4(acc[4], acc[5], acc[6], acc[7]);
            __syncthreads();

            if (tid < 256) {
                float4 z = bsv;
                const int jhc = cjl >> 1, jlc = cjl & 1;
                #pragma unroll
                for (int q = 0; q < 4; ++q) {
                    float4 v = *(const float4*)&zp[(q << 1) | jhc][cb][jlc << 2];
                    z.x += v.x; z.y += v.y; z.z += v.z; z.w += v.w;
                }
                float ig = sigm(z.x), fg = sigm(z.y);
                float gg = tanhf(z.z), og = sigm(z.w);
                c = fg * c + ig * gg;
                float hn = og * tanhf(c);
                sth(&h1T[(size_t)(t & (R1 - 1)) * NH * NB + (size_t)cj * NB + cbg], hn);
            }
            asm volatile("s_waitcnt vmcnt(0)" ::: "memory");
            __syncthreads();
            if (tid == 0) bump(ownc);
        }
    }

    // ---- end protocol: reset counters behind a real barrier (replay-safe) ----
    gridbar(1, false);
    if (gid == 0 && tid == 0) {
        __hip_atomic_store(&g_cnt0[0],  0u, __ATOMIC_RELAXED, __HIP_MEMORY_SCOPE_AGENT);
        __hip_atomic_store(&g_cnt0[32], 0u, __ATOMIC_RELAXED, __HIP_MEMORY_SCOPE_AGENT);
        __hip_atomic_store(&g_cnt1[0],  0u, __ATOMIC_RELAXED, __HIP_MEMORY_SCOPE_AGENT);
        __hip_atomic_store(&g_cnt1[32], 0u, __ATOMIC_RELAXED, __HIP_MEMORY_SCOPE_AGENT);
    }
    gridbar(2, true);
}

extern "C" void kernel_launch(void* const* d_in, const int* in_sizes, int n_in,
                              void* d_out, int out_size, void* d_ws, size_t ws_size,
                              hipStream_t stream)
{
    const float* x    = (const float*)d_in[0];
    const float* h0in = (const float*)d_in[1];
    const float* c0in = (const float*)d_in[2];
    const float* Wih0 = (const float*)d_in[3];
    const float* Whh0 = (const float*)d_in[4];
    const float* bih0 = (const float*)d_in[5];
    const float* bhh0 = (const float*)d_in[6];
    const float* Wih1 = (const float*)d_in[7];
    const float* Whh1 = (const float*)d_in[8];
    const float* bih1 = (const float*)d_in[9];
    const float* bhh1 = (const float*)d_in[10];
    const float* Wlin = (const float*)d_in[11];
    const float* blin = (const float*)d_in[12];
    float* out = (float*)d_out;

    float* h0T = (float*)d_ws;                  // [R0][NH][NB]
    float* h1T = h0T + (size_t)R0 * NH * NB;    // [R1][NH][NB]

    void* args[] = { &x, &h0in, &c0in, &Wih0, &Whh0, &bih0, &bhh0,
                     &Wih1, &Whh1, &bih1, &bhh1, &Wlin, &blin,
                     &out, &h0T, &h1T };
    hipLaunchCooperativeKernel((void*)lstm2, dim3(NWG), dim3(NTHR), args, 0, stream);
}

// Round 6
// 22426.688 us; speedup vs baseline: 1.6570x; 1.6570x over previous
//
#include <hip/hip_runtime.h>

constexpr int TT   = 2048;  // timesteps
constexpr int NB   = 128;   // batch
constexpr int NI   = 64;    // input size
constexpr int NH   = 256;   // hidden
constexpr int NGRP = 128;   // WGs per layer
constexpr int NWG  = 256;
constexpr int NTHR = 512;
constexpr int R0   = 8;     // h0 ring slots (layer 0 may run <=7 ahead)
constexpr int R1   = 16;    // h1 ring slots
constexpr int HLAG = 8;     // head lag: at layer-0 step s, head for u = s-8
constexpr int SLOT = (NH / 2) * NB;  // dwords per packed-bf16 h slot (64 KB)

// Aggregated monotone counters (one cacheline apart) + end-barrier state.
// Zero at load; reset at kernel end -> graph-replay safe.
__device__ unsigned g_c[64];          // g_c[0]=layer-0 publishes, g_c[32]=layer-1
__device__ unsigned g_cnt = 0, g_gen = 0;

__device__ __forceinline__ float sigm(float v) { return 1.0f / (1.0f + __expf(-v)); }
__device__ __forceinline__ float tanhfast(float v) {
    float e = __expf(2.0f * v);
    return 1.0f - 2.0f / (e + 1.0f);
}
__device__ __forceinline__ float asfl(unsigned u) { return __uint_as_float(u); }
__device__ __forceinline__ unsigned f2bf(float f) {   // RNE float->bf16 bits
    unsigned u = __float_as_uint(f);
    return (u + 0x7fffu + ((u >> 16) & 1u)) >> 16;
}

// LLC-coherent (agent-scope relaxed) accessors for cross-WG h data.
__device__ __forceinline__ unsigned long long ldq(const unsigned* p) {
    return __hip_atomic_load((const unsigned long long*)p, __ATOMIC_RELAXED,
                             __HIP_MEMORY_SCOPE_AGENT);
}
__device__ __forceinline__ unsigned ldd(const unsigned* p) {
    return __hip_atomic_load(p, __ATOMIC_RELAXED, __HIP_MEMORY_SCOPE_AGENT);
}
__device__ __forceinline__ void std_(unsigned* p, unsigned v) {
    __hip_atomic_store(p, v, __ATOMIC_RELAXED, __HIP_MEMORY_SCOPE_AGENT);
}
__device__ __forceinline__ void bump(unsigned* p) {
    (void)__hip_atomic_fetch_add(p, 1u, __ATOMIC_RELAXED, __HIP_MEMORY_SCOPE_AGENT);
}

// Wave 0 polls both counters in ONE load instruction (lane0 -> g_c[0],
// lane1 -> g_c[32]); loop until both targets met.
__device__ __forceinline__ void pollboth(unsigned n0, unsigned n1, int lane) {
    const unsigned* p = &g_c[(lane & 1) * 32];
    for (;;) {
        unsigned v = ldd(p);
        unsigned c0v = (unsigned)__shfl((int)v, 0);
        unsigned c1v = (unsigned)__shfl((int)v, 1);
        if (c0v >= n0 && c1v >= n1) return;
        __builtin_amdgcn_s_sleep(1);
    }
}

// Counter barrier, ONLY for the end-of-kernel reset protocol.
__device__ __forceinline__ void gridbar(unsigned k, bool last) {
    __syncthreads();
    if (threadIdx.x == 0) {
        __threadfence();
        unsigned a = __hip_atomic_fetch_add(&g_cnt, 1u, __ATOMIC_ACQ_REL,
                                            __HIP_MEMORY_SCOPE_AGENT);
        if (a == k * NWG - 1u) {
            if (last) {
                __hip_atomic_store(&g_cnt, 0u, __ATOMIC_RELAXED, __HIP_MEMORY_SCOPE_AGENT);
                __hip_atomic_store(&g_gen, 0u, __ATOMIC_RELEASE, __HIP_MEMORY_SCOPE_AGENT);
            } else {
                __hip_atomic_store(&g_gen, k, __ATOMIC_RELEASE, __HIP_MEMORY_SCOPE_AGENT);
            }
        } else if (!last) {
            while (__hip_atomic_load(&g_gen, __ATOMIC_RELAXED,
                                     __HIP_MEMORY_SCOPE_AGENT) < k)
                __builtin_amdgcn_s_sleep(1);
        }
        __threadfence();
    }
    __syncthreads();
}

// One FMA block: 8 weight rows (2 j x 4 gates) x one k, two b columns.
#define STEPQ(Q, HA, HB)                                   \
    acc[0]  += w00.Q * (HA); acc[1]  += w00.Q * (HB);      \
    acc[2]  += w01.Q * (HA); acc[3]  += w01.Q * (HB);      \
    acc[4]  += w02.Q * (HA); acc[5]  += w02.Q * (HB);      \
    acc[6]  += w03.Q * (HA); acc[7]  += w03.Q * (HB);      \
    acc[8]  += w10.Q * (HA); acc[9]  += w10.Q * (HB);      \
    acc[10] += w11.Q * (HA); acc[11] += w11.Q * (HB);      \
    acc[12] += w12.Q * (HA); acc[13] += w12.Q * (HB);      \
    acc[14] += w13.Q * (HA); acc[15] += w13.Q * (HB);

#define LOADW(W, K, kk)                                                        \
    float4 w00 = *(const float4*)((W) + (size_t)(0 * NH + j0    ) * (K) + (kk)); \
    float4 w01 = *(const float4*)((W) + (size_t)(1 * NH + j0    ) * (K) + (kk)); \
    float4 w02 = *(const float4*)((W) + (size_t)(2 * NH + j0    ) * (K) + (kk)); \
    float4 w03 = *(const float4*)((W) + (size_t)(3 * NH + j0    ) * (K) + (kk)); \
    float4 w10 = *(const float4*)((W) + (size_t)(0 * NH + j0 + 1) * (K) + (kk)); \
    float4 w11 = *(const float4*)((W) + (size_t)(1 * NH + j0 + 1) * (K) + (kk)); \
    float4 w12 = *(const float4*)((W) + (size_t)(2 * NH + j0 + 1) * (K) + (kk)); \
    float4 w13 = *(const float4*)((W) + (size_t)(3 * NH + j0 + 1) * (K) + (kk));

// Partial dot over a 64-long k slice of bf16 h packed [k/2][b][2].
// One dwordx2 = 2 k x 2 b. Weights fp32, L1-resident, wave-uniform rows.
__device__ __forceinline__ void partH_bf(const float* __restrict__ W, int j0,
                                         int kbase,
                                         const unsigned* __restrict__ hd,
                                         int lane, float* acc) {
    const unsigned* hp = hd + (size_t)(kbase >> 1) * NB + (lane << 1);
    #pragma unroll 4
    for (int i = 0; i < 16; ++i) {
        const int kk = kbase + (i << 2);
        LOADW(W, NH, kk)
        unsigned long long q0 = ldq(hp + (size_t)(2 * i) * NB);
        unsigned long long q1 = ldq(hp + (size_t)(2 * i + 1) * NB);
        unsigned d00 = (unsigned)q0, d01 = (unsigned)(q0 >> 32);
        unsigned d10 = (unsigned)q1, d11 = (unsigned)(q1 >> 32);
        STEPQ(x, asfl(d00 << 16),          asfl(d01 << 16))
        STEPQ(y, asfl(d00 & 0xffff0000u),  asfl(d01 & 0xffff0000u))
        STEPQ(z, asfl(d10 << 16),          asfl(d11 << 16))
        STEPQ(w, asfl(d10 & 0xffff0000u),  asfl(d11 & 0xffff0000u))
    }
}

// Partial dot over a 16-long k slice of x stored [b][k] fp32 (cached loads).
__device__ __forceinline__ void partX(const float* __restrict__ W, int j0,
                                      int k0, const float* __restrict__ xp,
                                      int lane, float* acc) {
    #pragma unroll
    for (int i4 = 0; i4 < 4; ++i4) {
        const int kk = k0 + (i4 << 2);
        LOADW(W, NI, kk)
        float4 xa = *(const float4*)(xp + (size_t)(lane << 1) * NI + kk);
        float4 xb = *(const float4*)(xp + (size_t)((lane << 1) + 1) * NI + kk);
        STEPQ(x, xa.x, xb.x)
        STEPQ(y, xa.y, xb.y)
        STEPQ(z, xa.z, xb.z)
        STEPQ(w, xa.w, xb.w)
    }
}

// Grid: 256 WGs x 512 thr, 1 WG/CU. gid<128: layer 0 (+head), else layer 1.
// WG g owns j0=2g, 2g+1 (8 gate rows) x all 128 b. Waves 0-3: Whh·h (64 k
// each); waves 4-7: Wih·x (L0) or Wih1·h0 (L1). Partials meet in LDS zp4;
// combine threads (tid<128, one per b) do gates for BOTH j and store one
// packed bf16 dword. c state lives in registers for all 2048 steps.
__global__ void __launch_bounds__(NTHR, 2) lstm2(
    const float* __restrict__ x,
    const float* __restrict__ h0in, const float* __restrict__ c0in,
    const float* __restrict__ Wih0, const float* __restrict__ Whh0,
    const float* __restrict__ bih0, const float* __restrict__ bhh0,
    const float* __restrict__ Wih1, const float* __restrict__ Whh1,
    const float* __restrict__ bih1, const float* __restrict__ bhh1,
    const float* __restrict__ Wlin, const float* __restrict__ blin,
    float* __restrict__ out,
    unsigned* __restrict__ h0d, unsigned* __restrict__ h1d)
{
    __shared__ __align__(16) float4 zp4[16 * NB];   // [wv*2+jl][b] gates, 32 KB
    __shared__ float red[4];
    __shared__ unsigned go_w;

    const int tid  = threadIdx.x;
    const int gid  = blockIdx.x;
    const bool is1 = gid >= NGRP;
    const int g    = is1 ? gid - NGRP : gid;
    const int j0   = g * 2;
    const int lane = tid & 63;
    const int wv   = __builtin_amdgcn_readfirstlane(tid >> 6);

    unsigned* ownc   = is1 ? &g_c[32] : &g_c[0];

    // ---- init: biases + c state + h(-1) publish (packed bf16) ----
    float4 bsA = make_float4(0, 0, 0, 0), bsB = bsA;
    float cA = 0.f, cB = 0.f;
    if (tid < 128) {
        const float* bi = is1 ? bih1 : bih0;
        const float* bh = is1 ? bhh1 : bhh0;
        bsA.x = bi[0 * NH + j0] + bh[0 * NH + j0];
        bsA.y = bi[1 * NH + j0] + bh[1 * NH + j0];
        bsA.z = bi[2 * NH + j0] + bh[2 * NH + j0];
        bsA.w = bi[3 * NH + j0] + bh[3 * NH + j0];
        bsB.x = bi[0 * NH + j0 + 1] + bh[0 * NH + j0 + 1];
        bsB.y = bi[1 * NH + j0 + 1] + bh[1 * NH + j0 + 1];
        bsB.z = bi[2 * NH + j0 + 1] + bh[2 * NH + j0 + 1];
        bsB.w = bi[3 * NH + j0 + 1] + bh[3 * NH + j0 + 1];
        const float* cbase = c0in + (is1 ? 1 : 0) * NB * NH + (size_t)tid * NH + j0;
        cA = cbase[0]; cB = cbase[1];
        const float* hbase = h0in + (is1 ? 1 : 0) * NB * NH + (size_t)tid * NH + j0;
        unsigned d = (f2bf(hbase[1]) << 16) | f2bf(hbase[0]);
        unsigned* hT = is1 ? h1d : h0d;
        const int islot = is1 ? (R1 - 1) : (R0 - 1);
        std_(hT + (size_t)islot * SLOT + (size_t)g * NB + tid, d);
    }
    if (tid == 0) go_w = 0;
    const float blv = blin[0];
    asm volatile("s_waitcnt vmcnt(0)" ::: "memory");
    __syncthreads();
    if (tid == 0) bump(ownc);   // counters reach 128 per layer after init

    if (!is1) {
        // ================= layer 0 (+ head, lag HLAG) =================
        for (int s = 0; s < TT + HLAG; ++s) {
            const unsigned tgt = (unsigned)(s + 1);
            unsigned need0 = (s < TT) ? 128u * (unsigned)(s + 1) : 0u;
            unsigned need1 = (s >= R0) ? 128u * (unsigned)(s - R0 + 2) : 0u;
            if (wv == 0) {
                pollboth(need0, need1, lane);
                if (lane == 0)
                    __hip_atomic_store(&go_w, tgt, __ATOMIC_RELAXED,
                                       __HIP_MEMORY_SCOPE_WORKGROUP);
            } else {
                while (__hip_atomic_load(&go_w, __ATOMIC_RELAXED,
                                         __HIP_MEMORY_SCOPE_WORKGROUP) < tgt) {}
            }

            if (s < TT) {
                float acc[16] = {0,0,0,0,0,0,0,0,0,0,0,0,0,0,0,0};
                if (wv < 4)
                    partH_bf(Whh0, j0, wv * 64,
                             h0d + (size_t)((s + R0 - 1) & (R0 - 1)) * SLOT, lane, acc);
                else
                    partX(Wih0, j0, (wv - 4) * 16, x + (size_t)s * NB * NI, lane, acc);
                const int base0 = ((wv << 1) + 0) * NB + (lane << 1);
                const int base1 = ((wv << 1) + 1) * NB + (lane << 1);
                zp4[base0]     = make_float4(acc[0],  acc[2],  acc[4],  acc[6]);
                zp4[base0 + 1] = make_float4(acc[1],  acc[3],  acc[5],  acc[7]);
                zp4[base1]     = make_float4(acc[8],  acc[10], acc[12], acc[14]);
                zp4[base1 + 1] = make_float4(acc[9],  acc[11], acc[13], acc[15]);
            }
            if (s >= HLAG && tid >= 256) {          // head partial for u = s-HLAG
                const int u = s - HLAG;
                const int k = tid - 256;
                unsigned d = ldd(h1d + (size_t)(u & (R1 - 1)) * SLOT
                                 + (size_t)(k >> 1) * NB + g);
                float hv = (k & 1) ? asfl(d & 0xffff0000u) : asfl(d << 16);
                float p = Wlin[k] * hv;
                #pragma unroll
                for (int off = 32; off; off >>= 1) p += __shfl_down(p, off);
                if (lane == 0) red[wv - 4] = p;
            }
            __syncthreads();

            if (s < TT && tid < 128) {              // combine both j, store packed
                float4 zA = bsA, zB = bsB;
                #pragma unroll
                for (int q = 0; q < 8; ++q) {
                    float4 a = zp4[(q * 2 + 0) * NB + tid];
                    float4 b = zp4[(q * 2 + 1) * NB + tid];
                    zA.x += a.x; zA.y += a.y; zA.z += a.z; zA.w += a.w;
                    zB.x += b.x; zB.y += b.y; zB.z += b.z; zB.w += b.w;
                }
                float iA = sigm(zA.x), fA = sigm(zA.y), gA = tanhfast(zA.z), oA = sigm(zA.w);
                cA = fA * cA + iA * gA;
                float hA = oA * tanhfast(cA);
                float iB = sigm(zB.x), fB = sigm(zB.y), gB = tanhfast(zB.z), oB = sigm(zB.w);
                cB = fB * cB + iB * gB;
                float hB = oB * tanhfast(cB);
                unsigned d = (f2bf(hB) << 16) | f2bf(hA);
                std_(h0d + (size_t)(s & (R0 - 1)) * SLOT + (size_t)g * NB + tid, d);
            }
            if (s >= HLAG && tid == 256)
                out[(size_t)(s - HLAG) * NB + g] = red[0] + red[1] + red[2] + red[3] + blv;

            asm volatile("s_waitcnt vmcnt(0)" ::: "memory");
            __syncthreads();
            if (s < TT && tid == 0) bump(&g_c[0]);
        }
    } else {
        // ================= layer 1 =================
        for (int t = 0; t < TT; ++t) {
            const unsigned tgt = (unsigned)(t + 1);
            unsigned need0 = 128u * (unsigned)(t + 2);   // h0(t) ready
            unsigned need1 = 128u * (unsigned)(t + 1);   // h1(t-1) ready
            if (wv == 0) {
                pollboth(need0, need1, lane);
                if (lane == 0)
                    __hip_atomic_store(&go_w, tgt, __ATOMIC_RELAXED,
                                       __HIP_MEMORY_SCOPE_WORKGROUP);
            } else {
                while (__hip_atomic_load(&go_w, __ATOMIC_RELAXED,
                                         __HIP_MEMORY_SCOPE_WORKGROUP) < tgt) {}
            }

            float acc[16] = {0,0,0,0,0,0,0,0,0,0,0,0,0,0,0,0};
            if (wv < 4)
                partH_bf(Wih1, j0, wv * 64,
                         h0d + (size_t)(t & (R0 - 1)) * SLOT, lane, acc);
            else
                partH_bf(Whh1, j0, (wv - 4) * 64,
                         h1d + (size_t)((t + R1 - 1) & (R1 - 1)) * SLOT, lane, acc);
            const int base0 = ((wv << 1) + 0) * NB + (lane << 1);
            const int base1 = ((wv << 1) + 1) * NB + (lane << 1);
            zp4[base0]     = make_float4(acc[0],  acc[2],  acc[4],  acc[6]);
            zp4[base0 + 1] = make_float4(acc[1],  acc[3],  acc[5],  acc[7]);
            zp4[base1]     = make_float4(acc[8],  acc[10], acc[12], acc[14]);
            zp4[base1 + 1] = make_float4(acc[9],  acc[11], acc[13], acc[15]);
            __syncthreads();

            if (tid < 128) {
                float4 zA = bsA, zB = bsB;
                #pragma unroll
                for (int q = 0; q < 8; ++q) {
                    float4 a = zp4[(q * 2 + 0) * NB + tid];
                    float4 b = zp4[(q * 2 + 1) * NB + tid];
                    zA.x += a.x; zA.y += a.y; zA.z += a.z; zA.w += a.w;
                    zB.x += b.x; zB.y += b.y; zB.z += b.z; zB.w += b.w;
                }
                float iA = sigm(zA.x), fA = sigm(zA.y), gA = tanhfast(zA.z), oA = sigm(zA.w);
                cA = fA * cA + iA * gA;
                float hA = oA * tanhfast(cA);
                float iB = sigm(zB.x), fB = sigm(zB.y), gB = tanhfast(zB.z), oB = sigm(zB.w);
                cB = fB * cB + iB * gB;
                float hB = oB * tanhfast(cB);
                unsigned d = (f2bf(hB) << 16) | f2bf(hA);
                std_(h1d + (size_t)(t & (R1 - 1)) * SLOT + (size_t)g * NB + tid, d);
            }
            asm volatile("s_waitcnt vmcnt(0)" ::: "memory");
            __syncthreads();
            if (tid == 0) bump(&g_c[32]);
        }
    }

    // ---- end protocol: reset counters behind a real barrier (replay-safe) ----
    gridbar(1, false);
    if (gid == 0 && tid == 0) {
        __hip_atomic_store(&g_c[0],  0u, __ATOMIC_RELAXED, __HIP_MEMORY_SCOPE_AGENT);
        __hip_atomic_store(&g_c[32], 0u, __ATOMIC_RELAXED, __HIP_MEMORY_SCOPE_AGENT);
    }
    gridbar(2, true);
}

extern "C" void kernel_launch(void* const* d_in, const int* in_sizes, int n_in,
                              void* d_out, int out_size, void* d_ws, size_t ws_size,
                              hipStream_t stream)
{
    const float* x    = (const float*)d_in[0];
    const float* h0in = (const float*)d_in[1];
    const float* c0in = (const float*)d_in[2];
    const float* Wih0 = (const float*)d_in[3];
    const float* Whh0 = (const float*)d_in[4];
    const float* bih0 = (const float*)d_in[5];
    const float* bhh0 = (const float*)d_in[6];
    const float* Wih1 = (const float*)d_in[7];
    const float* Whh1 = (const float*)d_in[8];
    const float* bih1 = (const float*)d_in[9];
    const float* bhh1 = (const float*)d_in[10];
    const float* Wlin = (const float*)d_in[11];
    const float* blin = (const float*)d_in[12];
    float* out = (float*)d_out;

    unsigned* h0d = (unsigned*)d_ws;            // [R0][NH/2][NB] packed bf16
    unsigned* h1d = h0d + (size_t)R0 * SLOT;    // [R1][NH/2][NB] packed bf16

    void* args[] = { &x, &h0in, &c0in, &Wih0, &Whh0, &bih0, &bhh0,
                     &Wih1, &Whh1, &bih1, &bhh1, &Wlin, &blin,
                     &out, &h0d, &h1d };
    hipLaunchCooperativeKernel((void*)lstm2, dim3(NWG), dim3(NTHR), args, 0, stream);
}